// Round 6
// baseline (197.124 us; speedup 1.0000x reference)
//
#include <hip/hip_runtime.h>
#include <hip/hip_bf16.h>

#define NTAG 64
#define TLEN 512
#define START_TAG 62
#define STOP_TAG 63
#define CHUNK 32
#define HALF (TLEN / 2)

typedef __attribute__((ext_vector_type(8))) short short8;   // 8 bf16 = 1 MFMA A/B frag
typedef __attribute__((ext_vector_type(4))) float f32x4;    // MFMA acc

__device__ __forceinline__ unsigned short f2bfu(float f) {
    __hip_bfloat16 h = __float2bfloat16(f);
    unsigned short u; __builtin_memcpy(&u, &h, 2); return u;
}
__device__ __forceinline__ unsigned pk2bf(float a, float b) {
    __hip_bfloat162 h = __float22bfloat162_rn(make_float2(a, b));
    unsigned u; __builtin_memcpy(&u, &h, 4); return u;
}

// One workgroup (128 thr = 2 waves) per batch. wave0: fwd t=0..255, wave1: bwd
// t=511..256, linear domain, exact pow2 renorm every 4 steps.
//
// Round-6: the 64x64 matvec is ONE wave's MFMA with the B operand's 16 columns
// all loading the same 64-entry bf16 state from LDS (c-independent addresses
// -> HW broadcast, conflict-free). All 16 D columns are then identical, so
// every lane holds the true result in C-layout — no masking, no transpose.
// Replaces round-5's 16 broadcast ds_read_b128 + 64 fma (~520 cyc/step) with
// 2 ds_read_b128 + 8 mfma (~120 cyc/step). Layouts per m89-verified mapping:
//   A[m=lane&15][k=quad*8+j], B[k=quad*8+j][n=lane&15],
//   C/D: col=lane&15, row=quad*4+reg.
__global__ __launch_bounds__(128) void crf_fwd_bwd(
    const float* __restrict__ emis,   // [B, T, L]
    const float* __restrict__ trans,  // [L, L]  trans[next, prev]
    float* __restrict__ out)          // [B]
{
    const int b    = blockIdx.x;
    const int tid  = threadIdx.x;
    const int lane = tid & 63;
    const int w    = tid >> 6;           // 0 = fwd, 1 = bwd
    const int q    = lane >> 4;          // quad
    const int c    = lane & 15;          // column / replica id

    __shared__ float lds[2 * 2 * CHUNK * NTAG];          // staged w=exp(emis), 32 KB
    __shared__ __align__(16) unsigned short xbf[2][NTAG]; // bf16 state per wave
    __shared__ float shv[2][NTAG];
    __shared__ int   shOff[2];

    const float L2E = 1.4426950408889634f;
    const float LN2 = 0.6931471805599453f;

    // ---- A fragments: E = exp(trans) as bf16, 4 row-tiles x 2 k-tiles ----
    //   fwd: M = E          (D[n][*] = sum_p E[n,p] x[p])
    //   bwd: M = E^T        (b[p]    = sum_n E[n,p] z[n])
    short8 Af[8];                         // [t*2 + K]
    #pragma unroll
    for (int t = 0; t < 4; ++t) {
        #pragma unroll
        for (int K = 0; K < 2; ++K) {
            short8 f;
            #pragma unroll
            for (int j = 0; j < 8; ++j) {
                int row = 16 * t + c;         // m
                int col = 32 * K + 8 * q + j; // k
                float tv = (w == 0) ? trans[row * NTAG + col]
                                    : trans[col * NTAG + row];
                f[j] = (short)f2bfu(exp2f(tv * L2E));
            }
            Af[t * 2 + K] = f;
        }
    }

    const float* eb = emis + (size_t)b * TLEN * NTAG;

    float4 r0, r1, r2, r3, r4, r5, r6, r7;
    #define LOAD_CHUNK(baseT)                                        \
        do {                                                         \
            const float4* gp = (const float4*)(eb + (baseT) * NTAG); \
            r0 = gp[0 * 64 + lane]; r1 = gp[1 * 64 + lane];          \
            r2 = gp[2 * 64 + lane]; r3 = gp[3 * 64 + lane];          \
            r4 = gp[4 * 64 + lane]; r5 = gp[5 * 64 + lane];          \
            r6 = gp[6 * 64 + lane]; r7 = gp[7 * 64 + lane];          \
        } while (0)
    #define EXP4(v) make_float4(exp2f((v).x * L2E), exp2f((v).y * L2E), \
                                exp2f((v).z * L2E), exp2f((v).w * L2E))
    #define STORE_CHUNK_EXP(bufp)                                    \
        do {                                                         \
            float4* b4 = (float4*)(bufp);                            \
            b4[0 * 64 + lane] = EXP4(r0); b4[1 * 64 + lane] = EXP4(r1); \
            b4[2 * 64 + lane] = EXP4(r2); b4[3 * 64 + lane] = EXP4(r3); \
            b4[4 * 64 + lane] = EXP4(r4); b4[5 * 64 + lane] = EXP4(r5); \
            b4[6 * 64 + lane] = EXP4(r6); b4[7 * 64 + lane] = EXP4(r7); \
        } while (0)

    float vout[16];
    int   off = 0;
    unsigned short* xs = xbf[w];

    // One recursion step. State (bf16[64]) in xs; emission chunk in buf.
    //   renorm ref = xs[0] written last step (broadcast u16 read, lane-uniform).
    //   B-frags at &xs[32K + 8q]: 16-B aligned, 4 distinct addrs (banks 4q),
    //   16-way same-addr broadcast -> conflict-free.
    //   em float4 at &buf[s*64+16t+4q]: broadcast across c, banks {16t+4q}.
    //   state write: lanes c==0 only (4 lanes, distinct banks), 4x ds_write_b64.
    #define STEP(buf, s)                                                    \
        do {                                                                \
            float rs_ = 1.0f;                                               \
            if (((s) & 3) == 0) {                                           \
                unsigned short ur_ = xs[0];                                 \
                int e_ = (int)((ur_ >> 7) & 0xffu) - 127;                   \
                off += e_;                                                  \
                rs_ = __uint_as_float((unsigned)(127 - e_) << 23);          \
            }                                                               \
            short8 b0_ = *(const short8*)&xs[8 * q];                        \
            short8 b1_ = *(const short8*)&xs[32 + 8 * q];                   \
            f32x4 z4_ = {0.f, 0.f, 0.f, 0.f};                               \
            f32x4 acc0_ = __builtin_amdgcn_mfma_f32_16x16x32_bf16(Af[0], b0_, z4_, 0, 0, 0); \
            f32x4 acc1_ = __builtin_amdgcn_mfma_f32_16x16x32_bf16(Af[2], b0_, z4_, 0, 0, 0); \
            f32x4 acc2_ = __builtin_amdgcn_mfma_f32_16x16x32_bf16(Af[4], b0_, z4_, 0, 0, 0); \
            f32x4 acc3_ = __builtin_amdgcn_mfma_f32_16x16x32_bf16(Af[6], b0_, z4_, 0, 0, 0); \
            acc0_ = __builtin_amdgcn_mfma_f32_16x16x32_bf16(Af[1], b1_, acc0_, 0, 0, 0); \
            acc1_ = __builtin_amdgcn_mfma_f32_16x16x32_bf16(Af[3], b1_, acc1_, 0, 0, 0); \
            acc2_ = __builtin_amdgcn_mfma_f32_16x16x32_bf16(Af[5], b1_, acc2_, 0, 0, 0); \
            acc3_ = __builtin_amdgcn_mfma_f32_16x16x32_bf16(Af[7], b1_, acc3_, 0, 0, 0); \
            const float* ebase_ = (buf) + (s) * NTAG + 4 * q;               \
            float4 e0_ = *(const float4*)(ebase_);                          \
            float4 e1_ = *(const float4*)(ebase_ + 16);                     \
            float4 e2_ = *(const float4*)(ebase_ + 32);                     \
            float4 e3_ = *(const float4*)(ebase_ + 48);                     \
            vout[0]  = acc0_[0] * (e0_.x * rs_);                            \
            vout[1]  = acc0_[1] * (e0_.y * rs_);                            \
            vout[2]  = acc0_[2] * (e0_.z * rs_);                            \
            vout[3]  = acc0_[3] * (e0_.w * rs_);                            \
            vout[4]  = acc1_[0] * (e1_.x * rs_);                            \
            vout[5]  = acc1_[1] * (e1_.y * rs_);                            \
            vout[6]  = acc1_[2] * (e1_.z * rs_);                            \
            vout[7]  = acc1_[3] * (e1_.w * rs_);                            \
            vout[8]  = acc2_[0] * (e2_.x * rs_);                            \
            vout[9]  = acc2_[1] * (e2_.y * rs_);                            \
            vout[10] = acc2_[2] * (e2_.z * rs_);                            \
            vout[11] = acc2_[3] * (e2_.w * rs_);                            \
            vout[12] = acc3_[0] * (e3_.x * rs_);                            \
            vout[13] = acc3_[1] * (e3_.y * rs_);                            \
            vout[14] = acc3_[2] * (e3_.z * rs_);                            \
            vout[15] = acc3_[3] * (e3_.w * rs_);                            \
            if (c == 0) {                                                   \
                uint2* xw_ = (uint2*)&xs[4 * q];                            \
                xw_[0]     = make_uint2(pk2bf(vout[0],  vout[1]),  pk2bf(vout[2],  vout[3]));  \
                *(uint2*)&xs[16 + 4 * q] = make_uint2(pk2bf(vout[4],  vout[5]),  pk2bf(vout[6],  vout[7]));  \
                *(uint2*)&xs[32 + 4 * q] = make_uint2(pk2bf(vout[8],  vout[9]),  pk2bf(vout[10], vout[11])); \
                *(uint2*)&xs[48 + 4 * q] = make_uint2(pk2bf(vout[12], vout[13]), pk2bf(vout[14], vout[15])); \
            }                                                               \
        } while (0)

    if (w == 0) {
        LOAD_CHUNK(0);
        #pragma clang loop unroll(disable)
        for (int ci = 0; ci < 8; ++ci) {
            float* buf = &lds[(ci & 1) * (CHUNK * NTAG)];
            STORE_CHUNK_EXP(buf);
            if (ci < 7) LOAD_CHUNK((ci + 1) * CHUNK);

            int s0 = 0;
            if (ci == 0) {
                // x_1[n] = exp(trans[n,START]) * w_0[n]  (t=0 folded into init)
                float x1 = exp2f(trans[lane * NTAG + START_TAG] * L2E) * buf[lane];
                xs[lane] = f2bfu(x1);
                s0 = 1;
            }
            #pragma clang loop unroll_count(4)
            for (int s = s0; s < CHUNK; ++s) STEP(buf, s);   // consumes w_1..w_255
        }
        // vout = x_256 (= alpha_255, linear, scaled by 2^off)
    } else {
        LOAD_CHUNK(HALF + 7 * CHUNK);
        #pragma clang loop unroll(disable)
        for (int i = 0; i < 8; ++i) {
            float* buf = &lds[(2 + (i & 1)) * (CHUNK * NTAG)];
            STORE_CHUNK_EXP(buf);
            if (i < 7) LOAD_CHUNK(HALF + (6 - i) * CHUNK);

            int s0 = CHUNK - 1;
            if (i == 0) {
                // z_511 = w_511 * b_511,  b_511 = exp(trans[STOP,:])
                float z = exp2f(trans[STOP_TAG * NTAG + lane] * L2E)
                        * buf[(CHUNK - 1) * NTAG + lane];
                xs[lane] = f2bfu(z);
                s0 = CHUNK - 2;
            }
            #pragma clang loop unroll_count(4)
            for (int s = s0; s >= 0; --s) STEP(buf, s);      // consumes w_510..w_256
        }
        // one bare matvec: b_255 = E^T z_256
        {
            short8 b0_ = *(const short8*)&xs[8 * q];
            short8 b1_ = *(const short8*)&xs[32 + 8 * q];
            f32x4 z4_ = {0.f, 0.f, 0.f, 0.f};
            #pragma unroll
            for (int t = 0; t < 4; ++t) {
                f32x4 a_ = __builtin_amdgcn_mfma_f32_16x16x32_bf16(Af[t * 2],     b0_, z4_, 0, 0, 0);
                a_       = __builtin_amdgcn_mfma_f32_16x16x32_bf16(Af[t * 2 + 1], b1_, a_,  0, 0, 0);
                vout[t * 4 + 0] = a_[0]; vout[t * 4 + 1] = a_[1];
                vout[t * 4 + 2] = a_[2]; vout[t * 4 + 3] = a_[3];
            }
        }
    }

    // publish per-wave final state (C-layout, replicated over c -> c==0 writes)
    if (c == 0) {
        #pragma unroll
        for (int t = 0; t < 4; ++t)
            *(float4*)&shv[w][16 * t + 4 * q] =
                make_float4(vout[4 * t], vout[4 * t + 1], vout[4 * t + 2], vout[4 * t + 3]);
    }
    if (lane == 0) shOff[w] = off;
    __syncthreads();

    if (w == 0) {
        // out = ln( sum_p x[p] * b[p] ) + ln2 * (offF + offB)
        float p = shv[0][lane] * shv[1][lane];
        #pragma unroll
        for (int d = 1; d < 64; d <<= 1) p += __shfl_xor(p, d, 64);
        if (lane == 0)
            out[b] = logf(p) + LN2 * (float)(shOff[0] + shOff[1]);
    }
}

extern "C" void kernel_launch(void* const* d_in, const int* in_sizes, int n_in,
                              void* d_out, int out_size, void* d_ws, size_t ws_size,
                              hipStream_t stream) {
    const float* emis  = (const float*)d_in[0];   // [512, 512, 64] f32
    const float* trans = (const float*)d_in[1];   // [64, 64] f32
    float* out = (float*)d_out;                   // [512] f32
    (void)in_sizes; (void)n_in; (void)out_size; (void)d_ws; (void)ws_size;
    crf_fwd_bwd<<<512, 128, 0, stream>>>(emis, trans, out);
}

// Round 8
// 145.022 us; speedup vs baseline: 1.3593x; 1.3593x over previous
//
#include <hip/hip_runtime.h>
#include <hip/hip_bf16.h>

#define NTAG 64
#define TLEN 512
#define START_TAG 62
#define STOP_TAG 63
#define CHUNK 32
#define HALF (TLEN / 2)

#if __has_builtin(__builtin_amdgcn_fdot2_f32_bf16)
#define USE_DOT2 1
typedef __attribute__((ext_vector_type(2))) __bf16 bfv2;
typedef __attribute__((ext_vector_type(8))) __bf16 bfv8;
#endif

__device__ __forceinline__ unsigned short f2bfu(float f) {
    __hip_bfloat16 h = __float2bfloat16(f);
    unsigned short u; __builtin_memcpy(&u, &h, 2); return u;
}
#ifdef USE_DOT2
__device__ __forceinline__ __bf16 f2bf(float f) {
    unsigned short u = f2bfu(f); __bf16 b; __builtin_memcpy(&b, &u, 2); return b;
}
#endif

// One workgroup (128 thr = 2 waves) per batch. wave0: fwd (consumes w_0..255),
// wave1: bwd (seed z_511 = S*w_511, 255 steps w_510..256, + one bare matvec).
// Linear domain, exact pow2 renorm every step (ref = state[0]'s exponent).
//
// Round-8 fix vs round 7: the renorm reference is guarded against a ZERO
// state[0]. The fwd seed is an indicator (state[0] = 0.0 -> exponent field 0
// -> e_=-127 -> rs_=2^127 -> overflow -> inf -> inf*0 = NaN in the dots).
// Exponent field 0 now means "no rescale". state[0] > 0 from step 1 on.
//
// Design (round 7): state is bf16 in LDS — 8 wave-uniform ds_read_b128
// (HW broadcast, conflict-free) deliver it; 32 v_dot2_f32_bf16 (f32 acc)
// do the 64-wide matvec. Replaced round-5's 16 f32 reads + 64 fma
// (DS-delivery-bound at ~731 cyc/step, 78 us).
__global__ __launch_bounds__(128) void crf_fwd_bwd(
    const float* __restrict__ emis,   // [B, T, L]
    const float* __restrict__ trans,  // [L, L]  trans[next, prev]
    float* __restrict__ out)          // [B]
{
    const int b    = blockIdx.x;
    const int tid  = threadIdx.x;
    const int lane = tid & 63;
    const int w    = tid >> 6;  // 0 = fwd, 1 = bwd

    __shared__ float lds[2 * 2 * CHUNK * NTAG];   // staged w = exp(emis), 32 KB
#ifdef USE_DOT2
    __shared__ __align__(16) unsigned short xbf[2][NTAG];  // bf16 state per wave
    unsigned short* xs = xbf[w];
#else
    __shared__ __align__(16) float xf32[2][NTAG];          // f32 state per wave
    float* xs = xf32[w];
#endif
    __shared__ float shv[2][NTAG];

    const float L2E = 1.4426950408889634f;
    const float LN2 = 0.6931471805599453f;

    // E = exp(trans), one row per lane.  fwd: E[lane,k]; bwd: E[k,lane].
    // Masked entries (-10000) flush to exactly 0.
#ifdef USE_DOT2
    bfv2 Epk[NTAG / 2];
    #pragma unroll
    for (int k2 = 0; k2 < NTAG / 2; ++k2) {
        float e0, e1;
        if (w == 0) {
            e0 = exp2f(trans[lane * NTAG + 2 * k2]     * L2E);
            e1 = exp2f(trans[lane * NTAG + 2 * k2 + 1] * L2E);
        } else {
            e0 = exp2f(trans[(2 * k2) * NTAG + lane]     * L2E);
            e1 = exp2f(trans[(2 * k2 + 1) * NTAG + lane] * L2E);
        }
        bfv2 p; p[0] = f2bf(e0); p[1] = f2bf(e1);
        Epk[k2] = p;
    }
#else
    float E[NTAG];
    #pragma unroll
    for (int k = 0; k < NTAG; ++k)
        E[k] = exp2f(((w == 0) ? trans[lane * NTAG + k]
                               : trans[k * NTAG + lane]) * L2E);
#endif

    const float* eb = emis + (size_t)b * TLEN * NTAG;

    float4 r0, r1, r2, r3, r4, r5, r6, r7;
    #define LOAD_CHUNK(baseT)                                        \
        do {                                                         \
            const float4* gp = (const float4*)(eb + (baseT) * NTAG); \
            r0 = gp[0 * 64 + lane]; r1 = gp[1 * 64 + lane];          \
            r2 = gp[2 * 64 + lane]; r3 = gp[3 * 64 + lane];          \
            r4 = gp[4 * 64 + lane]; r5 = gp[5 * 64 + lane];          \
            r6 = gp[6 * 64 + lane]; r7 = gp[7 * 64 + lane];          \
        } while (0)
    #define EXP4(v) make_float4(exp2f((v).x * L2E), exp2f((v).y * L2E), \
                                exp2f((v).z * L2E), exp2f((v).w * L2E))
    #define STORE_CHUNK_EXP(bufp)                                    \
        do {                                                         \
            float4* b4 = (float4*)(bufp);                            \
            b4[0 * 64 + lane] = EXP4(r0); b4[1 * 64 + lane] = EXP4(r1); \
            b4[2 * 64 + lane] = EXP4(r2); b4[3 * 64 + lane] = EXP4(r3); \
            b4[4 * 64 + lane] = EXP4(r4); b4[5 * 64 + lane] = EXP4(r5); \
            b4[6 * 64 + lane] = EXP4(r6); b4[7 * 64 + lane] = EXP4(r7); \
        } while (0)

#ifdef USE_DOT2
    // 8 wave-uniform ds_read_b128 deliver the whole bf16 state (HW broadcast,
    // conflict-free); 32 dot2 (f32 acc). ref exponent from state[0]'s bits,
    // GUARDED: exponent field 0 (zero/denormal) -> no rescale.
    #define PAIR(X, i) __builtin_shufflevector(X, X, 2 * (i), 2 * (i) + 1)
    #define DOTQ(acc, X, base)                                                     \
        acc = __builtin_amdgcn_fdot2_f32_bf16(Epk[(base) + 0], PAIR(X, 0), acc, false); \
        acc = __builtin_amdgcn_fdot2_f32_bf16(Epk[(base) + 1], PAIR(X, 1), acc, false); \
        acc = __builtin_amdgcn_fdot2_f32_bf16(Epk[(base) + 2], PAIR(X, 2), acc, false); \
        acc = __builtin_amdgcn_fdot2_f32_bf16(Epk[(base) + 3], PAIR(X, 3), acc, false);
    #define MATVEC_REF(ssum, e_)                                     \
        do {                                                         \
            const bfv8* xq_ = (const bfv8*)xs;                       \
            bfv8 X0 = xq_[0], X1 = xq_[1], X2 = xq_[2], X3 = xq_[3]; \
            bfv8 X4 = xq_[4], X5 = xq_[5], X6 = xq_[6], X7 = xq_[7]; \
            unsigned short ru_;                                      \
            { __bf16 rb_ = X0[0]; __builtin_memcpy(&ru_, &rb_, 2); } \
            int ef_ = (int)((ru_ >> 7) & 0xffu);                     \
            e_ = (ef_ == 0) ? 0 : ef_ - 127;                         \
            float a0 = 0.f, a1 = 0.f, a2 = 0.f, a3 = 0.f;            \
            DOTQ(a0, X0, 0)  DOTQ(a1, X1, 4)                         \
            DOTQ(a2, X2, 8)  DOTQ(a3, X3, 12)                        \
            DOTQ(a0, X4, 16) DOTQ(a1, X5, 20)                        \
            DOTQ(a2, X6, 24) DOTQ(a3, X7, 28)                        \
            ssum = (a0 + a1) + (a2 + a3);                            \
        } while (0)
    #define WRITE_STATE(v) (xs[lane] = f2bfu(v))
#else
    #define MATVEC_REF(ssum, e_)                                     \
        do {                                                         \
            const float4* xq_ = (const float4*)xs;                   \
            float4 xv_[16];                                          \
            _Pragma("unroll")                                        \
            for (int j = 0; j < 16; ++j) xv_[j] = xq_[j];            \
            int ef_ = (int)((__float_as_uint(xv_[0].x) >> 23) & 0xffu); \
            e_ = (ef_ == 0) ? 0 : ef_ - 127;                         \
            float a0=0.f,a1=0.f,a2=0.f,a3=0.f;                       \
            float a4=0.f,a5=0.f,a6=0.f,a7=0.f;                       \
            _Pragma("unroll")                                        \
            for (int j = 0; j < 16; j += 2) {                        \
                a0 = fmaf(xv_[j].x,     E[4*j + 0], a0);             \
                a1 = fmaf(xv_[j].y,     E[4*j + 1], a1);             \
                a2 = fmaf(xv_[j].z,     E[4*j + 2], a2);             \
                a3 = fmaf(xv_[j].w,     E[4*j + 3], a3);             \
                a4 = fmaf(xv_[j + 1].x, E[4*j + 4], a4);             \
                a5 = fmaf(xv_[j + 1].y, E[4*j + 5], a5);             \
                a6 = fmaf(xv_[j + 1].z, E[4*j + 6], a6);             \
                a7 = fmaf(xv_[j + 1].w, E[4*j + 7], a7);             \
            }                                                        \
            ssum = ((a0 + a1) + (a2 + a3)) + ((a4 + a5) + (a6 + a7)); \
        } while (0)
    #define WRITE_STATE(v) (xs[lane] = (v))
#endif

    // One recursion step: x_new = (E . x) * em * 2^-e, every-step renorm.
    #define STEP(buf, s)                                             \
        do {                                                         \
            float em_ = (buf)[(s) * NTAG + lane];                    \
            float ssum_; int e_;                                     \
            MATVEC_REF(ssum_, e_);                                   \
            off += e_;                                               \
            float rs_ = __uint_as_float((unsigned)(127 - e_) << 23); \
            x = ssum_ * em_ * rs_;                                   \
            WRITE_STATE(x);                                          \
        } while (0)

    float x = 0.0f;
    int   off = 0;   // accumulated power-of-2 offset (exact, lane-uniform)

    if (w == 0) {
        // seed a_0 = indicator(START)
        WRITE_STATE(lane == START_TAG ? 1.0f : 0.0f);

        LOAD_CHUNK(0);
        #pragma clang loop unroll(disable)
        for (int ci = 0; ci < 8; ++ci) {
            float* buf = &lds[(ci & 1) * (CHUNK * NTAG)];
            STORE_CHUNK_EXP(buf);
            if (ci < 7) LOAD_CHUNK((ci + 1) * CHUNK);   // in flight ~32 steps

            #pragma clang loop unroll_count(4)
            for (int s = 0; s < CHUNK; ++s) STEP(buf, s);  // w_0..w_255
        }
        // x = alpha_255 (linear, scaled by 2^off)
    } else {
        float Sv = exp2f(trans[STOP_TAG * NTAG + lane] * L2E);  // exp(trans[STOP,:])

        LOAD_CHUNK(HALF + 7 * CHUNK);
        #pragma clang loop unroll(disable)
        for (int i = 0; i < 8; ++i) {
            float* buf = &lds[(2 + (i & 1)) * (CHUNK * NTAG)];
            STORE_CHUNK_EXP(buf);
            if (i < 7) LOAD_CHUNK(HALF + (6 - i) * CHUNK);

            int s0 = CHUNK - 1;
            if (i == 0) {
                // seed z_511 = S * w_511 (w_511 = buf[31*NTAG+lane], staged above)
                WRITE_STATE(Sv * buf[(CHUNK - 1) * NTAG + lane]);
                s0 = CHUNK - 2;
            }
            #pragma clang loop unroll_count(4)
            for (int s = s0; s >= 0; --s) STEP(buf, s);    // w_510..w_256
        }
        // one bare matvec: beta = E^T z_256 (renorm folded in, exact)
        {
            float ssum_; int e_;
            MATVEC_REF(ssum_, e_);
            off += e_;
            x = ssum_ * __uint_as_float((unsigned)(127 - e_) << 23);
        }
    }

    // merge in log2 domain; off folded directly in (lane-uniform)
    shv[w][lane] = log2f(x) + (float)off;   // -inf for masked tags, safe
    __syncthreads();

    if (w == 0) {
        float v = shv[0][lane] + shv[1][lane];
        float m = v;
        #pragma unroll
        for (int d = 1; d < 64; d <<= 1) m = fmaxf(m, __shfl_xor(m, d, 64));
        float e = exp2f(v - m);
        #pragma unroll
        for (int d = 1; d < 64; d <<= 1) e += __shfl_xor(e, d, 64);
        if (lane == 0) out[b] = LN2 * (m + log2f(e));
    }
}

extern "C" void kernel_launch(void* const* d_in, const int* in_sizes, int n_in,
                              void* d_out, int out_size, void* d_ws, size_t ws_size,
                              hipStream_t stream) {
    const float* emis  = (const float*)d_in[0];   // [512, 512, 64] f32
    const float* trans = (const float*)d_in[1];   // [64, 64] f32
    float* out = (float*)d_out;                   // [512] f32
    (void)in_sizes; (void)n_in; (void)out_size; (void)d_ws; (void)ws_size;
    crf_fwd_bwd<<<512, 128, 0, stream>>>(emis, trans, out);
}